// Round 8
// baseline (232.552 us; speedup 1.0000x reference)
//
#include <hip/hip_runtime.h>
#include <cstdint>
#include <cstddef>

#define B_ 256
#define IW_ 3072
#define L_ 8
#define NN_ 7
#define FCIN_ 16384
#define OUTW_ 10
#define ICST 40            // ushorts per (row,col) cell: 32 ic + 8 pad
#define YPLANE (324 * ICST)

typedef short short8 __attribute__((ext_vector_type(8)));
typedef float f32x4 __attribute__((ext_vector_type(4)));

__device__ __forceinline__ ushort f2bf(float x) {
    uint u = __float_as_uint(x);
    return (ushort)((u + 0x7fffu + ((u >> 16) & 1u)) >> 16);
}
__device__ __forceinline__ float bf2f(ushort b) { return __uint_as_float(((uint)b) << 16); }

// ---------- repack conv1 weights into MFMA frag-linear hi/lo bf16 ----------
__global__ void k_repack_w1f(const float* __restrict__ w1, ushort* __restrict__ w1fh,
                             ushort* __restrict__ w1fl) {
    int i = blockIdx.x * 256 + threadIdx.x;
    if (i >= 16384) return;
    int j    = i & 7;
    int lane = (i >> 3) & 63;
    int mt   = (i >> 9) & 3;
    int l    = i >> 11;
    int fr = lane & 15, fq = lane >> 4;
    int oc = mt * 16 + fr;
    int k = fq * 8 + j;
    float w = (k < 27) ? w1[(size_t)(l * 64 + oc) * 27 + k] : 0.f;
    ushort hb = f2bf(w);
    w1fh[i] = hb;
    w1fl[i] = f2bf(w - bf2f(hb));
}

// ---------- repack conv2 weights: [l8][icc2][tap9][mt4][lane64][j8] ----------
__global__ void k_repack_w2(const float* __restrict__ w2, ushort* __restrict__ w2h,
                            ushort* __restrict__ w2l) {
    int i = blockIdx.x * 256 + threadIdx.x;
    if (i >= 294912) return;
    int j    = i & 7;
    int lane = (i >> 3) & 63;
    int mt   = (i >> 9) & 3;
    int tap  = (i >> 11) % 9;
    int icc  = (i / 18432) & 1;
    int l    = i / 36864;
    int fr = lane & 15, fq = lane >> 4;
    int oc = mt * 16 + fr;
    int ic = icc * 32 + fq * 8 + j;
    float w = w2[(((size_t)l * 64 + oc) * 64 + ic) * 9 + tap];
    ushort hb = f2bf(w);
    w2h[i] = hb;
    w2l[i] = f2bf(w - bf2f(hb));
}

// ---------- mixture ----------
__global__ __launch_bounds__(256) void k_mixture(const float* __restrict__ x, const float* __restrict__ nw,
                                                 const float* __restrict__ nb, float* __restrict__ mix) {
    __shared__ float red[4 * NN_];
    __shared__ float bes[NN_];
    int b = blockIdx.x, tid = threadIdx.x;
    const float* xb = x + (size_t)b * IW_;
    float p[NN_];
#pragma unroll
    for (int n = 0; n < NN_; ++n) p[n] = 0.f;
    for (int i = tid; i < IW_; i += 256) {
        float xv = xb[i];
#pragma unroll
        for (int n = 0; n < NN_; ++n) p[n] = fmaf(xv, nw[n * IW_ + i], p[n]);
    }
#pragma unroll
    for (int n = 0; n < NN_; ++n) {
        float v = p[n];
        for (int off = 32; off > 0; off >>= 1) v += __shfl_xor(v, off);
        if ((tid & 63) == 0) red[(tid >> 6) * NN_ + n] = v;
    }
    __syncthreads();
    if (tid < NN_) {
        float s = red[tid] + red[NN_ + tid] + red[2 * NN_ + tid] + red[3 * NN_ + tid] + nb[tid];
        bes[tid] = 1.f / (1.f + expf(-s));
    }
    __syncthreads();
    if (tid < L_) {
        int leaf = tid;
        float b0 = bes[0];
        float t0 = ((leaf >> 2) & 1) ? b0 : 1.f - b0;
        float b1v = bes[1 + ((leaf >> 2) & 1)];
        float t1 = ((leaf >> 1) & 1) ? b1v : 1.f - b1v;
        float b2v = bes[3 + ((leaf >> 1) & 3)];
        float t2 = (leaf & 1) ? b2v : 1.f - b2v;
        mix[b * L_ + leaf] = t0 * t1 * t2;
    }
}

// ---------- conv1 (MFMA im2col) + pool + relu -> y1 hi/lo compact [s][l][icc][pos256][ic32] ----------
// block = sample, 512 thr / 8 waves. Per (l,icc): 2 mtiles -> LDS compact tile -> coalesced copy-out.
__global__ __launch_bounds__(512, 2) void k_conv1(const float* __restrict__ x,
                                                  const ushort* __restrict__ w1fh, const ushort* __restrict__ w1fl,
                                                  const float* __restrict__ cb1,
                                                  ushort* __restrict__ y1h, ushort* __restrict__ y1l, int boff) {
    __shared__ float xpad[3 * 34 * 34];          // 13.9 KB
    __shared__ __align__(16) ushort tile[2 * 8192];  // 32 KB: [plane][pos256][ic32]
    int tid = threadIdx.x;
    int bl = blockIdx.x;
    int b = boff + bl;
    int lane = tid & 63, wid = tid >> 6;
    int fr = lane & 15, fq = lane >> 4;

    for (int i = tid; i < 3 * 34 * 34; i += 512) xpad[i] = 0.f;
    __syncthreads();
    for (int i = tid; i < 3072; i += 512) {
        int ch = i >> 10, rr = (i >> 5) & 31, cc = i & 31;
        xpad[(ch * 34 + rr + 1) * 34 + cc + 1] = x[(size_t)b * IW_ + i];
    }
    __syncthreads();

    // leaf-invariant im2col B-frags in registers (wave owns pre-pool ntiles wid*8..wid*8+7)
    short8 Bh[8], Bl[8];
#pragma unroll
    for (int i = 0; i < 8; ++i) {
        int nt = wid * 8 + i;
        int pos = nt * 16 + fr;
        int r = pos >> 5, c = pos & 31;
#pragma unroll
        for (int j = 0; j < 8; ++j) {
            int k = fq * 8 + j;
            float xv = 0.f;
            if (k < 27) {
                int ic = k / 9;
                int tap = k - ic * 9;
                int dr = tap / 3, dc = tap - dr * 3;
                xv = xpad[(ic * 34 + r + dr) * 34 + (c + dc)];
            }
            ushort hb = f2bf(xv);
            Bh[i][j] = (short)hb;
            Bl[i][j] = (short)f2bf(xv - bf2f(hb));
        }
    }
    __syncthreads();

    for (int s = 0; s < 16; ++s) {
        int l = s >> 1, icc = s & 1;
#pragma unroll
        for (int mt2 = 0; mt2 < 2; ++mt2) {
            int mtg = icc * 2 + mt2;
            short8 ah = *(const short8*)(w1fh + ((size_t)(l * 4 + mtg) * 64 + lane) * 8);
            short8 al = *(const short8*)(w1fl + ((size_t)(l * 4 + mtg) * 64 + lane) * 8);
            f32x4 a1[8];
#pragma unroll
            for (int i = 0; i < 8; ++i) {
                f32x4 t = (f32x4)0.f;
                t = __builtin_amdgcn_mfma_f32_16x16x32_bf16(ah, Bh[i], t, 0, 0, 0);
                t = __builtin_amdgcn_mfma_f32_16x16x32_bf16(ah, Bl[i], t, 0, 0, 0);
                t = __builtin_amdgcn_mfma_f32_16x16x32_bf16(al, Bh[i], t, 0, 0, 0);
                a1[i] = t;
            }
            float4 bias4 = *(const float4*)(cb1 + l * 64 + mtg * 16 + fq * 4);
            float bb[4] = {bias4.x, bias4.y, bias4.z, bias4.w};
#pragma unroll
            for (int g4 = 0; g4 < 4; ++g4) {
                int i = (g4 & 1) + (g4 >> 1) * 4;   // {0,1,4,5}; pool partner i+2
                ushort hb[4], lb[4];
#pragma unroll
                for (int j2 = 0; j2 < 4; ++j2) {
                    float m0 = fmaxf(a1[i][j2], a1[i + 2][j2]);
                    float m1 = fmaxf(m0, __shfl_xor(m0, 1));
                    float v = fmaxf(m1 + bb[j2], 0.f);
                    ushort h = f2bf(v);
                    hb[j2] = h;
                    lb[j2] = f2bf(v - bf2f(h));
                }
                if ((fr & 1) == 0) {
                    int pr = 2 * wid + (i >> 2);
                    int pc = ((i & 1) * 16 + fr) >> 1;
                    int off = (pr * 16 + pc) * 32 + mt2 * 16 + fq * 4;
                    uint2 H, Lw;
                    H.x = (uint)hb[0] | ((uint)hb[1] << 16); H.y = (uint)hb[2] | ((uint)hb[3] << 16);
                    Lw.x = (uint)lb[0] | ((uint)lb[1] << 16); Lw.y = (uint)lb[2] | ((uint)lb[3] << 16);
                    *(uint2*)&tile[off] = H;
                    *(uint2*)&tile[8192 + off] = Lw;
                }
            }
        }
        __syncthreads();
        size_t base = ((size_t)(bl * 8 + l) * 2 + icc) * 8192;
#pragma unroll
        for (int k = 0; k < 4; ++k) {
            int idx = k * 512 + tid;          // 0..2047 uint4 chunks
            int plane = idx >> 10, j = idx & 1023;
            uint4 v = *(const uint4*)&tile[plane * 8192 + j * 8];
            *(uint4*)((plane ? y1l : y1h) + base + j * 8) = v;
        }
        __syncthreads();
    }
}

// ---------- conv2: block = (sample, oc-half). dc/rr-restructured MFMA loop ----------
// 256 thr / 4 waves; wave = 4-row output band (band0 = wid*4), both mtiles of the 32-oc half.
// Per step (l,icc): stage y1 chunk into zero-bordered halo tile, then
// for dc: load 12 A-frags; for 6 input rows: 1 B-read (hi+lo), reuse for up to 3 row-taps.
__global__ __launch_bounds__(256, 3) void k_conv2(const ushort* __restrict__ y1h, const ushort* __restrict__ y1l,
                                                  const ushort* __restrict__ w2h, const ushort* __restrict__ w2l,
                                                  const float* __restrict__ cb2, const float* __restrict__ mixw,
                                                  float* __restrict__ out1, int boff, int nwg) {
    __shared__ __align__(16) ushort yh[YPLANE];   // [18][18][ICST]
    __shared__ __align__(16) ushort yl[YPLANE];
    int tid = threadIdx.x;
    // bijective XCD swizzle: consecutive logical ids land on same XCD chunk
    int orig = blockIdx.x;
    int q = nwg >> 3, r = nwg & 7;
    int xcd = orig & 7;
    int wgid = (xcd < r ? xcd * (q + 1) : r * (q + 1) + (xcd - r) * q) + (orig >> 3);
    int bl = wgid >> 1, och = wgid & 1;
    int bg = boff + bl;
    int lane = tid & 63, wid = tid >> 6;
    int fr = lane & 15, fq = lane >> 4;
    int band0 = wid * 4;

    {   // zero tiles once; borders stay zero (staging writes interior only)
        uint4 z; z.x = z.y = z.z = z.w = 0u;
        for (int i = tid; i < (2 * YPLANE) / 8; i += 256) {
            if (i < YPLANE / 8) ((uint4*)yh)[i] = z; else ((uint4*)yl)[i - YPLANE / 8] = z;
        }
    }
    __syncthreads();

    f32x4 acc[2][4], oacc[2][4];
#pragma unroll
    for (int m = 0; m < 2; ++m)
#pragma unroll
        for (int rl = 0; rl < 4; ++rl) { acc[m][rl] = (f32x4)0.f; oacc[m][rl] = (f32x4)0.f; }

    for (int s = 0; s < 16; ++s) {
        int l = s >> 1, icc = s & 1;
        // ---- stage y1 (32 KB) into halo tiles ----
        size_t srcb = ((size_t)(bl * 8 + l) * 2 + icc) * 8192;
#pragma unroll
        for (int it = 0; it < 8; ++it) {
            int c4 = it * 256 + tid;             // 0..2047
            int plane = c4 >> 10, rem = c4 & 1023;
            int pos = rem >> 2, kc = rem & 3;
            const ushort* sp = (plane ? y1l : y1h) + srcb + (size_t)pos * 32 + kc * 8;
            uint4 v = *(const uint4*)sp;
            int rr = pos >> 4, cc = pos & 15;
            int off = ((rr + 1) * 18 + (cc + 1)) * ICST + kc * 8;
            *(uint4*)((plane ? yl : yh) + off) = v;
        }
        __syncthreads();

        // ---- compute: dc-major, input-row B reuse ----
#pragma unroll
        for (int dc = 0; dc < 3; ++dc) {
            short8 Ah[2][3], Al[2][3];
#pragma unroll
            for (int dr = 0; dr < 3; ++dr) {
                int tap = dr * 3 + dc;
#pragma unroll
                for (int m = 0; m < 2; ++m) {
                    int mt = och * 2 + m;
                    Ah[m][dr] = *(const short8*)(w2h + ((size_t)(((l * 2 + icc) * 9 + tap) * 4 + mt) * 64 + lane) * 8);
                    Al[m][dr] = *(const short8*)(w2l + ((size_t)(((l * 2 + icc) * 9 + tap) * 4 + mt) * 64 + lane) * 8);
                }
            }
#pragma unroll
            for (int rr = 0; rr < 6; ++rr) {
                int off = ((band0 + rr) * 18 + (fr + dc)) * ICST + fq * 8;
                short8 bh = *(const short8*)(yh + off);
                short8 bv = *(const short8*)(yl + off);
#pragma unroll
                for (int dr = 0; dr < 3; ++dr) {
                    int rl = rr - dr;
                    if (rl >= 0 && rl < 4) {
#pragma unroll
                        for (int m = 0; m < 2; ++m) {
                            acc[m][rl] = __builtin_amdgcn_mfma_f32_16x16x32_bf16(Ah[m][dr], bh, acc[m][rl], 0, 0, 0);
                            acc[m][rl] = __builtin_amdgcn_mfma_f32_16x16x32_bf16(Ah[m][dr], bv, acc[m][rl], 0, 0, 0);
                            acc[m][rl] = __builtin_amdgcn_mfma_f32_16x16x32_bf16(Al[m][dr], bh, acc[m][rl], 0, 0, 0);
                        }
                    }
                }
            }
        }
        if (icc) {  // leaf epilogue
            float mx = mixw[(size_t)bg * 8 + l];
#pragma unroll
            for (int m = 0; m < 2; ++m)
#pragma unroll
                for (int j = 0; j < 4; ++j) {
                    float bias = cb2[l * 64 + och * 32 + m * 16 + fq * 4 + j];
#pragma unroll
                    for (int rl = 0; rl < 4; ++rl) {
                        float v = fmaxf(acc[m][rl][j] + bias, 0.f);
                        oacc[m][rl][j] = fmaf(mx, v, oacc[m][rl][j]);
                        acc[m][rl][j] = 0.f;
                    }
                }
        }
        __syncthreads();
    }

    // ---- store out1 [bl][64][256] ----
#pragma unroll
    for (int m = 0; m < 2; ++m)
#pragma unroll
        for (int rl = 0; rl < 4; ++rl)
#pragma unroll
            for (int j = 0; j < 4; ++j) {
                int oc = och * 32 + m * 16 + fq * 4 + j;
                int pos = (band0 + rl) * 16 + fr;
                out1[((size_t)bl * 64 + oc) * 256 + pos] = oacc[m][rl][j];
            }
}

// ---------- fc ----------
__global__ __launch_bounds__(256) void k_fc(const float* __restrict__ out1, const float* __restrict__ fcw,
                                            const float* __restrict__ fcb, float* __restrict__ out, int boff) {
    __shared__ float red[4][OUTW_];
    int tid = threadIdx.x;
    int bl = blockIdx.x;
    const float4* flat = (const float4*)(out1 + (size_t)bl * FCIN_);
    float pj[OUTW_];
#pragma unroll
    for (int j = 0; j < OUTW_; ++j) pj[j] = 0.f;
    for (int i = tid; i < FCIN_ / 4; i += 256) {
        float4 v = flat[i];
#pragma unroll
        for (int j = 0; j < OUTW_; ++j) {
            float4 w = ((const float4*)(fcw + (size_t)j * FCIN_))[i];
            pj[j] += v.x * w.x + v.y * w.y + v.z * w.z + v.w * w.w;
        }
    }
#pragma unroll
    for (int j = 0; j < OUTW_; ++j) {
        float v = pj[j];
        for (int off = 32; off > 0; off >>= 1) v += __shfl_xor(v, off);
        if ((tid & 63) == 0) red[tid >> 6][j] = v;
    }
    __syncthreads();
    if (tid < OUTW_) {
        float s = red[0][tid] + red[1][tid] + red[2][tid] + red[3][tid] + fcb[tid];
        out[(size_t)(boff + bl) * OUTW_ + tid] = s;
    }
}

extern "C" void kernel_launch(void* const* d_in, const int* in_sizes, int n_in,
                              void* d_out, int out_size, void* d_ws, size_t ws_size,
                              hipStream_t stream) {
    const float* x   = (const float*)d_in[0];
    const float* nw  = (const float*)d_in[1];
    const float* nb  = (const float*)d_in[2];
    const float* w1  = (const float*)d_in[3];
    const float* cb1 = (const float*)d_in[4];
    const float* w2  = (const float*)d_in[5];
    const float* cb2 = (const float*)d_in[6];
    const float* fcw = (const float*)d_in[7];
    const float* fcb = (const float*)d_in[8];
    float* out = (float*)d_out;

    float*  ws   = (float*)d_ws;
    float*  mix  = ws;                        // 2048 f
    ushort* w1fh = (ushort*)(mix + 2048);     // 16384 us
    ushort* w1fl = w1fh + 16384;              // 16384 us
    ushort* w2h  = w1fl + 16384;              // 294912 us
    ushort* w2l  = w2h + 294912;              // 294912 us

    // fixed bytes: 2048*4 + 2*16384*2 + 2*294912*2 = 1253376
    // per sample: out1 65536 B + y1 hi/lo 2*262144 B = 589824 B
    long avail = (long)ws_size - 1253376L;
    int Bc = (int)(avail / 589824L);
    if (Bc > B_) Bc = B_;
    if (Bc < 1) Bc = 1;

    float*  out1 = (float*)(w2l + 294912);            // Bc*16384 f
    ushort* y1h  = (ushort*)(out1 + (size_t)Bc * 16384); // Bc*131072 us
    ushort* y1l  = y1h + (size_t)Bc * 131072;

    k_repack_w1f<<<16384 / 256, 256, 0, stream>>>(w1, w1fh, w1fl);
    k_repack_w2<<<294912 / 256, 256, 0, stream>>>(w2, w2h, w2l);
    k_mixture<<<B_, 256, 0, stream>>>(x, nw, nb, mix);

    for (int boff = 0; boff < B_; boff += Bc) {
        int bc = (B_ - boff < Bc) ? (B_ - boff) : Bc;
        k_conv1<<<bc, 512, 0, stream>>>(x, w1fh, w1fl, cb1, y1h, y1l, boff);
        k_conv2<<<bc * 2, 256, 0, stream>>>(y1h, y1l, w2h, w2l, cb2, mix, out1, boff, bc * 2);
        k_fc<<<bc, 256, 0, stream>>>(out1, fcw, fcb, out, boff);
    }
}

// Round 9
// 215.259 us; speedup vs baseline: 1.0803x; 1.0803x over previous
//
#include <hip/hip_runtime.h>
#include <cstdint>
#include <cstddef>

#define B_ 256
#define IW_ 3072
#define L_ 8
#define NN_ 7
#define FCIN_ 16384
#define OUTW_ 10
#define ICST 72            // ushorts per (row,col) cell: 64 ic + 8 pad (144B = 9 granules, odd -> spread)
#define YT (324 * ICST)    // 23328 ushorts = 46.66 KB

typedef short short8 __attribute__((ext_vector_type(8)));
typedef float f32x4 __attribute__((ext_vector_type(4)));

__device__ __forceinline__ ushort f2bf(float x) {
    uint u = __float_as_uint(x);
    return (ushort)((u + 0x7fffu + ((u >> 16) & 1u)) >> 16);
}
__device__ __forceinline__ float bf2f(ushort b) { return __uint_as_float(((uint)b) << 16); }

// ---------- repack conv1 weights into MFMA frag-linear hi/lo bf16 ----------
// layout: [l8][mt4][lane64][j8]; oc = mt*16 + (lane&15); k = (lane>>4)*8 + j (k=ic*9+tap, 27..31 pad)
__global__ void k_repack_w1f(const float* __restrict__ w1, ushort* __restrict__ w1fh,
                             ushort* __restrict__ w1fl) {
    int i = blockIdx.x * 256 + threadIdx.x;
    if (i >= 16384) return;
    int j    = i & 7;
    int lane = (i >> 3) & 63;
    int mt   = (i >> 9) & 3;
    int l    = i >> 11;
    int fr = lane & 15, fq = lane >> 4;
    int oc = mt * 16 + fr;
    int k = fq * 8 + j;
    float w = (k < 27) ? w1[(size_t)(l * 64 + oc) * 27 + k] : 0.f;
    ushort hb = f2bf(w);
    w1fh[i] = hb;
    w1fl[i] = f2bf(w - bf2f(hb));
}

// ---------- repack conv2 weights: [l8][icc2][tap9][mt4][lane64][j8] ----------
__global__ void k_repack_w2(const float* __restrict__ w2, ushort* __restrict__ w2h,
                            ushort* __restrict__ w2l) {
    int i = blockIdx.x * 256 + threadIdx.x;
    if (i >= 294912) return;
    int j    = i & 7;
    int lane = (i >> 3) & 63;
    int mt   = (i >> 9) & 3;
    int tap  = (i >> 11) % 9;
    int icc  = (i / 18432) & 1;
    int l    = i / 36864;
    int fr = lane & 15, fq = lane >> 4;
    int oc = mt * 16 + fr;
    int ic = icc * 32 + fq * 8 + j;
    float w = w2[(((size_t)l * 64 + oc) * 64 + ic) * 9 + tap];
    ushort hb = f2bf(w);
    w2h[i] = hb;
    w2l[i] = f2bf(w - bf2f(hb));
}

// ---------- mixture ----------
__global__ __launch_bounds__(256) void k_mixture(const float* __restrict__ x, const float* __restrict__ nw,
                                                 const float* __restrict__ nb, float* __restrict__ mix) {
    __shared__ float red[4 * NN_];
    __shared__ float bes[NN_];
    int b = blockIdx.x, tid = threadIdx.x;
    const float* xb = x + (size_t)b * IW_;
    float p[NN_];
#pragma unroll
    for (int n = 0; n < NN_; ++n) p[n] = 0.f;
    for (int i = tid; i < IW_; i += 256) {
        float xv = xb[i];
#pragma unroll
        for (int n = 0; n < NN_; ++n) p[n] = fmaf(xv, nw[n * IW_ + i], p[n]);
    }
#pragma unroll
    for (int n = 0; n < NN_; ++n) {
        float v = p[n];
        for (int off = 32; off > 0; off >>= 1) v += __shfl_xor(v, off);
        if ((tid & 63) == 0) red[(tid >> 6) * NN_ + n] = v;
    }
    __syncthreads();
    if (tid < NN_) {
        float s = red[tid] + red[NN_ + tid] + red[2 * NN_ + tid] + red[3 * NN_ + tid] + nb[tid];
        bes[tid] = 1.f / (1.f + expf(-s));
    }
    __syncthreads();
    if (tid < L_) {
        int leaf = tid;
        float b0 = bes[0];
        float t0 = ((leaf >> 2) & 1) ? b0 : 1.f - b0;
        float b1v = bes[1 + ((leaf >> 2) & 1)];
        float t1 = ((leaf >> 1) & 1) ? b1v : 1.f - b1v;
        float b2v = bes[3 + ((leaf >> 1) & 3)];
        float t2 = (leaf & 1) ? b2v : 1.f - b2v;
        mix[b * L_ + leaf] = t0 * t1 * t2;
    }
}

// ---------- fused conv1/conv2, single-bf16 y, 2-product W-split, full-leaf steps ----------
// grid = bc*2: block = (sample, leaf-half), 4 full-leaf steps. 512 thr / 8 waves.
// y tile [18][18][72] single plane (zero borders = halo). Target <=128 regs -> 2 blocks/CU.
// conv2 wave tile: mts {2g,2g+1}, nts {4ng..4ng+3} processed 2-at-a-time (acc 16 regs).
__global__ __launch_bounds__(512, 2) void k_fused(const float* __restrict__ x,
                                                  const ushort* __restrict__ w1fh, const ushort* __restrict__ w1fl,
                                                  const float* __restrict__ cb1,
                                                  const ushort* __restrict__ w2h, const ushort* __restrict__ w2l,
                                                  const float* __restrict__ cb2, const float* __restrict__ mixw,
                                                  float* __restrict__ out1, int boff) {
    __shared__ __align__(16) ushort yt[YT];      // 46.66 KB; xpad aliases front in prologue
    float* xpad = (float*)yt;                    // 3*34*34 floats = 13.9 KB

    int tid = threadIdx.x;
    int bl = blockIdx.x >> 1, half = blockIdx.x & 1;
    int b = boff + bl;
    int lane = tid & 63, wid = tid >> 6;
    int fr = lane & 15, fq = lane >> 4;
    int g = wid & 1, ng = wid >> 1;

    // ---- prologue: xpad zero + fill ----
    for (int i = tid; i < 3 * 34 * 34; i += 512) xpad[i] = 0.f;
    __syncthreads();
    for (int i = tid; i < 3072; i += 512) {
        int ch = i >> 10, rr = (i >> 5) & 31, cc = i & 31;
        xpad[(ch * 34 + rr + 1) * 34 + cc + 1] = x[(size_t)b * IW_ + i];
    }
    __syncthreads();

    // ---- leaf-invariant conv1 im2col B-frags, single bf16 (RTN) ----
    short8 Bh[8];
#pragma unroll
    for (int i = 0; i < 8; ++i) {
        int nt = wid * 8 + i;
        int pos = nt * 16 + fr;          // pre-pool position, row-major 32x32
        int r = pos >> 5, c = pos & 31;
#pragma unroll
        for (int j = 0; j < 8; ++j) {
            int k = fq * 8 + j;          // k = ic*9 + tap
            float xv = 0.f;
            if (k < 27) {
                int ic = k / 9;
                int tap = k - ic * 9;
                int dr = tap / 3, dc = tap - dr * 3;
                xv = xpad[(ic * 34 + r + dr) * 34 + (c + dc)];
            }
            Bh[i][j] = (short)f2bf(xv);
        }
    }
    __syncthreads();
    {   // zero y tile (borders stay zero forever)
        uint4 z; z.x = z.y = z.z = z.w = 0u;
        for (int i = tid; i < YT / 8; i += 512) ((uint4*)yt)[i] = z;
    }
    __syncthreads();

    f32x4 oacc[2][4];
#pragma unroll
    for (int m = 0; m < 2; ++m)
#pragma unroll
        for (int nl = 0; nl < 4; ++nl) oacc[m][nl] = (f32x4)0.f;

    for (int s = 0; s < 4; ++s) {
        int l = half * 4 + s;

        // ---- conv1 phase: all 64 chans of leaf l into y tile ----
#pragma unroll
        for (int mtg = 0; mtg < 4; ++mtg) {
            short8 ah = *(const short8*)(w1fh + ((size_t)(l * 4 + mtg) * 64 + lane) * 8);
            short8 al = *(const short8*)(w1fl + ((size_t)(l * 4 + mtg) * 64 + lane) * 8);
            float4 bias4 = *(const float4*)(cb1 + l * 64 + mtg * 16 + fq * 4);
            float bb[4] = {bias4.x, bias4.y, bias4.z, bias4.w};
#pragma unroll
            for (int pi = 0; pi < 4; ++pi) {
                int i = (pi & 1) + (pi >> 1) * 4;   // {0,1,4,5}; pool partner i+2
                f32x4 t0 = (f32x4)0.f, t2 = (f32x4)0.f;
                t0 = __builtin_amdgcn_mfma_f32_16x16x32_bf16(ah, Bh[i], t0, 0, 0, 0);
                t0 = __builtin_amdgcn_mfma_f32_16x16x32_bf16(al, Bh[i], t0, 0, 0, 0);
                t2 = __builtin_amdgcn_mfma_f32_16x16x32_bf16(ah, Bh[i + 2], t2, 0, 0, 0);
                t2 = __builtin_amdgcn_mfma_f32_16x16x32_bf16(al, Bh[i + 2], t2, 0, 0, 0);
                ushort hb[4];
#pragma unroll
                for (int j2 = 0; j2 < 4; ++j2) {
                    float m0 = fmaxf(t0[j2], t2[j2]);
                    float m1 = fmaxf(m0, __shfl_xor(m0, 1));
                    float v = fmaxf(m1 + bb[j2], 0.f);
                    hb[j2] = f2bf(v);
                }
                if ((fr & 1) == 0) {
                    int pr = 2 * wid + (i >> 2);
                    int pc = (i & 1) * 8 + (fr >> 1);
                    int off = ((pr + 1) * 18 + (pc + 1)) * ICST + mtg * 16 + fq * 4;
                    uint2 H;
                    H.x = (uint)hb[0] | ((uint)hb[1] << 16);
                    H.y = (uint)hb[2] | ((uint)hb[3] << 16);
                    *(uint2*)&yt[off] = H;
                }
            }
        }
        __syncthreads();

        // ---- conv2 phase: full K=64 per nl-pair, leaf epilogue inline ----
        float mx = mixw[(size_t)b * 8 + l];
#pragma unroll
        for (int p = 0; p < 2; ++p) {
            f32x4 a2[2][2];
            a2[0][0] = (f32x4)0.f; a2[0][1] = (f32x4)0.f;
            a2[1][0] = (f32x4)0.f; a2[1][1] = (f32x4)0.f;
#pragma unroll
            for (int icc = 0; icc < 2; ++icc)
#pragma unroll
                for (int tap = 0; tap < 9; ++tap) {
                    int kh = tap / 3, kw = tap - kh * 3;
                    size_t wbase = ((size_t)(((l * 2 + icc) * 9 + tap) * 4 + 2 * g) * 64 + lane) * 8;
                    short8 Ah0 = *(const short8*)(w2h + wbase);
                    short8 Al0 = *(const short8*)(w2l + wbase);
                    short8 Ah1 = *(const short8*)(w2h + wbase + 512);
                    short8 Al1 = *(const short8*)(w2l + wbase + 512);
#pragma unroll
                    for (int q = 0; q < 2; ++q) {
                        int nt = 4 * ng + 2 * p + q;
                        int off = ((nt + kh) * 18 + (fr + kw)) * ICST + icc * 32 + fq * 8;
                        short8 bh = *(const short8*)(yt + off);
                        a2[0][q] = __builtin_amdgcn_mfma_f32_16x16x32_bf16(Ah0, bh, a2[0][q], 0, 0, 0);
                        a2[0][q] = __builtin_amdgcn_mfma_f32_16x16x32_bf16(Al0, bh, a2[0][q], 0, 0, 0);
                        a2[1][q] = __builtin_amdgcn_mfma_f32_16x16x32_bf16(Ah1, bh, a2[1][q], 0, 0, 0);
                        a2[1][q] = __builtin_amdgcn_mfma_f32_16x16x32_bf16(Al1, bh, a2[1][q], 0, 0, 0);
                    }
                }
#pragma unroll
            for (int m = 0; m < 2; ++m) {
                float4 b4 = *(const float4*)(cb2 + l * 64 + (2 * g + m) * 16 + fq * 4);
                float bb2[4] = {b4.x, b4.y, b4.z, b4.w};
#pragma unroll
                for (int j = 0; j < 4; ++j)
#pragma unroll
                    for (int q = 0; q < 2; ++q) {
                        float v = fmaxf(a2[m][q][j] + bb2[j], 0.f);
                        oacc[m][2 * p + q][j] = fmaf(mx, v, oacc[m][2 * p + q][j]);
                    }
            }
        }
        __syncthreads();
    }

    // ---- store partial out1 [blk][64 oc][256 pos] ----
#pragma unroll
    for (int m = 0; m < 2; ++m)
#pragma unroll
        for (int nl = 0; nl < 4; ++nl)
#pragma unroll
            for (int j = 0; j < 4; ++j) {
                int oc = (2 * g + m) * 16 + fq * 4 + j;
                int pos = (4 * ng + nl) * 16 + fr;
                out1[((size_t)blockIdx.x * 64 + oc) * 256 + pos] = oacc[m][nl][j];
            }
}

// ---------- fc: sum two leaf-half partials, then [16384] @ [10][16384]^T + b ----------
__global__ __launch_bounds__(256) void k_fc(const float* __restrict__ out1, const float* __restrict__ fcw,
                                            const float* __restrict__ fcb, float* __restrict__ out, int boff) {
    __shared__ float red[4][OUTW_];
    int tid = threadIdx.x;
    int bl = blockIdx.x;
    const float4* f0 = (const float4*)(out1 + (size_t)(bl * 2) * FCIN_);
    const float4* f1 = (const float4*)(out1 + (size_t)(bl * 2 + 1) * FCIN_);
    float pj[OUTW_];
#pragma unroll
    for (int j = 0; j < OUTW_; ++j) pj[j] = 0.f;
    for (int i = tid; i < FCIN_ / 4; i += 256) {
        float4 v0 = f0[i], v1 = f1[i];
        float4 v;
        v.x = v0.x + v1.x; v.y = v0.y + v1.y; v.z = v0.z + v1.z; v.w = v0.w + v1.w;
#pragma unroll
        for (int j = 0; j < OUTW_; ++j) {
            float4 w = ((const float4*)(fcw + (size_t)j * FCIN_))[i];
            pj[j] += v.x * w.x + v.y * w.y + v.z * w.z + v.w * w.w;
        }
    }
#pragma unroll
    for (int j = 0; j < OUTW_; ++j) {
        float v = pj[j];
        for (int off = 32; off > 0; off >>= 1) v += __shfl_xor(v, off);
        if ((tid & 63) == 0) red[tid >> 6][j] = v;
    }
    __syncthreads();
    if (tid < OUTW_) {
        float s = red[0][tid] + red[1][tid] + red[2][tid] + red[3][tid] + fcb[tid];
        out[(size_t)(boff + bl) * OUTW_ + tid] = s;
    }
}

extern "C" void kernel_launch(void* const* d_in, const int* in_sizes, int n_in,
                              void* d_out, int out_size, void* d_ws, size_t ws_size,
                              hipStream_t stream) {
    const float* x   = (const float*)d_in[0];
    const float* nw  = (const float*)d_in[1];
    const float* nb  = (const float*)d_in[2];
    const float* w1  = (const float*)d_in[3];
    const float* cb1 = (const float*)d_in[4];
    const float* w2  = (const float*)d_in[5];
    const float* cb2 = (const float*)d_in[6];
    const float* fcw = (const float*)d_in[7];
    const float* fcb = (const float*)d_in[8];
    float* out = (float*)d_out;

    float*  ws   = (float*)d_ws;
    float*  mix  = ws;                        // 2048 f
    ushort* w1fh = (ushort*)(mix + 2048);     // 16384 us
    ushort* w1fl = w1fh + 16384;              // 16384 us
    ushort* w2h  = w1fl + 16384;              // 294912 us
    ushort* w2l  = w2h + 294912;              // 294912 us
    float*  out1 = (float*)(w2l + 294912);    // Bc * 2 * 16384 f

    // fixed bytes: 2048*4 + 2*16384*2 + 2*294912*2 = 1253376; out1 per sample = 131072 B
    long avail = (long)ws_size - 1253376L;
    int Bc = (int)(avail / 131072L);
    if (Bc > B_) Bc = B_;
    if (Bc < 1) Bc = 1;

    k_repack_w1f<<<16384 / 256, 256, 0, stream>>>(w1, w1fh, w1fl);
    k_repack_w2<<<294912 / 256, 256, 0, stream>>>(w2, w2h, w2l);
    k_mixture<<<B_, 256, 0, stream>>>(x, nw, nb, mix);

    for (int boff = 0; boff < B_; boff += Bc) {
        int bc = (B_ - boff < Bc) ? (B_ - boff) : Bc;
        k_fused<<<bc * 2, 512, 0, stream>>>(x, w1fh, w1fl, cb1, w2h, w2l, cb2, mix, out1, boff);
        k_fc<<<bc, 256, 0, stream>>>(out1, fcw, fcb, out, boff);
    }
}

// Round 10
// 140.522 us; speedup vs baseline: 1.6549x; 1.5319x over previous
//
#include <hip/hip_runtime.h>
#include <cstdint>
#include <cstddef>

#define B_ 256
#define IW_ 3072
#define L_ 8
#define NN_ 7
#define FCIN_ 16384
#define OUTW_ 10
#define ICST 40            // ushorts per (row,col) cell: 32 ic + 8 pad
#define YPLANE (324 * ICST)

typedef short short8 __attribute__((ext_vector_type(8)));
typedef float f32x4 __attribute__((ext_vector_type(4)));

__device__ __forceinline__ ushort f2bf(float x) {
    uint u = __float_as_uint(x);
    return (ushort)((u + 0x7fffu + ((u >> 16) & 1u)) >> 16);
}
__device__ __forceinline__ float bf2f(ushort b) { return __uint_as_float(((uint)b) << 16); }

// ---------- repack conv1 weights into MFMA frag-linear hi/lo bf16 ----------
// layout: [l8][mt4][lane64][j8]; oc = mt*16 + (lane&15); k = (lane>>4)*8 + j (k=ic*9+tap, 27..31 pad)
__global__ void k_repack_w1f(const float* __restrict__ w1, ushort* __restrict__ w1fh,
                             ushort* __restrict__ w1fl) {
    int i = blockIdx.x * 256 + threadIdx.x;
    if (i >= 16384) return;
    int j    = i & 7;
    int lane = (i >> 3) & 63;
    int mt   = (i >> 9) & 3;
    int l    = i >> 11;
    int fr = lane & 15, fq = lane >> 4;
    int oc = mt * 16 + fr;
    int k = fq * 8 + j;
    float w = (k < 27) ? w1[(size_t)(l * 64 + oc) * 27 + k] : 0.f;
    ushort hb = f2bf(w);
    w1fh[i] = hb;
    w1fl[i] = f2bf(w - bf2f(hb));
}

// ---------- repack conv2 weights: [l8][icc2][tap9][mt4][lane64][j8] hi/lo ----------
__global__ void k_repack_w2(const float* __restrict__ w2, ushort* __restrict__ w2h,
                            ushort* __restrict__ w2l) {
    int i = blockIdx.x * 256 + threadIdx.x;
    if (i >= 294912) return;
    int j    = i & 7;
    int lane = (i >> 3) & 63;
    int mt   = (i >> 9) & 3;
    int tap  = (i >> 11) % 9;
    int icc  = (i / 18432) & 1;
    int l    = i / 36864;
    int fr = lane & 15, fq = lane >> 4;
    int oc = mt * 16 + fr;
    int ic = icc * 32 + fq * 8 + j;
    float w = w2[(((size_t)l * 64 + oc) * 64 + ic) * 9 + tap];
    ushort hb = f2bf(w);
    w2h[i] = hb;
    w2l[i] = f2bf(w - bf2f(hb));
}

// ---------- mixture ----------
__global__ __launch_bounds__(256) void k_mixture(const float* __restrict__ x, const float* __restrict__ nw,
                                                 const float* __restrict__ nb, float* __restrict__ mix) {
    __shared__ float red[4 * NN_];
    __shared__ float bes[NN_];
    int b = blockIdx.x, tid = threadIdx.x;
    const float* xb = x + (size_t)b * IW_;
    float p[NN_];
#pragma unroll
    for (int n = 0; n < NN_; ++n) p[n] = 0.f;
    for (int i = tid; i < IW_; i += 256) {
        float xv = xb[i];
#pragma unroll
        for (int n = 0; n < NN_; ++n) p[n] = fmaf(xv, nw[n * IW_ + i], p[n]);
    }
#pragma unroll
    for (int n = 0; n < NN_; ++n) {
        float v = p[n];
        for (int off = 32; off > 0; off >>= 1) v += __shfl_xor(v, off);
        if ((tid & 63) == 0) red[(tid >> 6) * NN_ + n] = v;
    }
    __syncthreads();
    if (tid < NN_) {
        float s = red[tid] + red[NN_ + tid] + red[2 * NN_ + tid] + red[3 * NN_ + tid] + nb[tid];
        bes[tid] = 1.f / (1.f + expf(-s));
    }
    __syncthreads();
    if (tid < L_) {
        int leaf = tid;
        float b0 = bes[0];
        float t0 = ((leaf >> 2) & 1) ? b0 : 1.f - b0;
        float b1v = bes[1 + ((leaf >> 2) & 1)];
        float t1 = ((leaf >> 1) & 1) ? b1v : 1.f - b1v;
        float b2v = bes[3 + ((leaf >> 1) & 3)];
        float t2 = (leaf & 1) ? b2v : 1.f - b2v;
        mix[b * L_ + leaf] = t0 * t1 * t2;
    }
}

// ---------- fused conv1/conv2 (R6 chassis, single-bf16 y, 2-product W-split, dc/rr conv2) ----------
// block = sample (grid 256 = 1/CU), 512 thr / 8 waves, 16 steps (8 leaves x 2 icc).
// y tile: ONE plane [18][18][ICST] (25.9 KB), zero borders = halo.
// conv1: 2 mtiles/step, 2 MFMA per ntile (Whi,Wlo x Bh).
// conv2: wave tile mts{2g,2g+1} x rows{4ng..4ng+3}; dc-major loop reads each input row ONCE
//        per column-shift (18 b128 reads/step, was 72) and reuses it for 3 row-taps in regs.
__global__ __launch_bounds__(512, 2) void k_fused(const float* __restrict__ x,
                                                  const ushort* __restrict__ w1fh, const ushort* __restrict__ w1fl,
                                                  const float* __restrict__ cb1,
                                                  const ushort* __restrict__ w2h, const ushort* __restrict__ w2l,
                                                  const float* __restrict__ cb2, const float* __restrict__ mixw,
                                                  float* __restrict__ out1, int boff) {
    __shared__ __align__(16) ushort yt[YPLANE];   // 25.9 KB; xpad aliases front in prologue
    float* xpad = (float*)yt;                     // 3*34*34 floats = 13.9 KB < plane

    int tid = threadIdx.x;
    int bl = blockIdx.x;
    int b = boff + bl;
    int lane = tid & 63, wid = tid >> 6;
    int fr = lane & 15, fq = lane >> 4;
    int g = wid & 1, ng = wid >> 1;               // conv2: mts {2g,2g+1}, rows {4ng..4ng+3}

    // ---- prologue: xpad zero + fill ----
    for (int i = tid; i < 3 * 34 * 34; i += 512) xpad[i] = 0.f;
    __syncthreads();
    for (int i = tid; i < 3072; i += 512) {
        int ch = i >> 10, rr = (i >> 5) & 31, cc = i & 31;
        xpad[(ch * 34 + rr + 1) * 34 + cc + 1] = x[(size_t)b * IW_ + i];
    }
    __syncthreads();

    // ---- leaf-invariant conv1 im2col B-frags, single bf16 (RTN) ----
    short8 Bh[8];
#pragma unroll
    for (int i = 0; i < 8; ++i) {
        int nt = wid * 8 + i;
        int pos = nt * 16 + fr;          // pre-pool position, row-major 32x32
        int r = pos >> 5, c = pos & 31;
#pragma unroll
        for (int j = 0; j < 8; ++j) {
            int k = fq * 8 + j;          // k = ic*9 + tap
            float xv = 0.f;
            if (k < 27) {
                int ic = k / 9;
                int tap = k - ic * 9;
                int dr = tap / 3, dc = tap - dr * 3;
                xv = xpad[(ic * 34 + r + dr) * 34 + (c + dc)];
            }
            Bh[i][j] = (short)f2bf(xv);
        }
    }
    __syncthreads();
    {   // zero y plane (borders stay zero forever)
        uint4 z; z.x = z.y = z.z = z.w = 0u;
        for (int i = tid; i < YPLANE / 8; i += 512) ((uint4*)yt)[i] = z;
    }
    __syncthreads();

    f32x4 acc[2][4], oacc[2][4];
#pragma unroll
    for (int m = 0; m < 2; ++m)
#pragma unroll
        for (int rl = 0; rl < 4; ++rl) { acc[m][rl] = (f32x4)0.f; oacc[m][rl] = (f32x4)0.f; }

    for (int s = 0; s < 16; ++s) {
        int l = s >> 1, icc = s & 1;

        // ---- conv1 phase: 32 chans (2 mtiles) of this icc chunk into y tile ----
#pragma unroll
        for (int mt2 = 0; mt2 < 2; ++mt2) {
            int mtg = icc * 2 + mt2;
            short8 ah = *(const short8*)(w1fh + ((size_t)(l * 4 + mtg) * 64 + lane) * 8);
            short8 al = *(const short8*)(w1fl + ((size_t)(l * 4 + mtg) * 64 + lane) * 8);
            f32x4 a1[8];
#pragma unroll
            for (int i = 0; i < 8; ++i) {
                f32x4 t = (f32x4)0.f;
                t = __builtin_amdgcn_mfma_f32_16x16x32_bf16(ah, Bh[i], t, 0, 0, 0);
                t = __builtin_amdgcn_mfma_f32_16x16x32_bf16(al, Bh[i], t, 0, 0, 0);
                a1[i] = t;
            }
            float4 bias4 = *(const float4*)(cb1 + l * 64 + mtg * 16 + fq * 4);
            float bb[4] = {bias4.x, bias4.y, bias4.z, bias4.w};
#pragma unroll
            for (int g4 = 0; g4 < 4; ++g4) {
                int i = (g4 & 1) + (g4 >> 1) * 4;   // {0,1,4,5}; pool partner i+2
                ushort hb[4];
#pragma unroll
                for (int j2 = 0; j2 < 4; ++j2) {
                    float m0 = fmaxf(a1[i][j2], a1[i + 2][j2]);
                    float m1 = fmaxf(m0, __shfl_xor(m0, 1));
                    float v = fmaxf(m1 + bb[j2], 0.f);
                    hb[j2] = f2bf(v);
                }
                if ((fr & 1) == 0) {
                    int pr = 2 * wid + (i >> 2);
                    int pc = ((i & 1) * 16 + fr) >> 1;
                    int off = ((pr + 1) * 18 + (pc + 1)) * ICST + mt2 * 16 + fq * 4;
                    uint2 H;
                    H.x = (uint)hb[0] | ((uint)hb[1] << 16);
                    H.y = (uint)hb[2] | ((uint)hb[3] << 16);
                    *(uint2*)&yt[off] = H;
                }
            }
        }
        __syncthreads();

        // ---- conv2 phase: dc-major, input-row reuse across row-taps ----
#pragma unroll
        for (int dc = 0; dc < 3; ++dc) {
            short8 Ah[2][3], Al[2][3];
#pragma unroll
            for (int dr = 0; dr < 3; ++dr) {
                int tap = dr * 3 + dc;
#pragma unroll
                for (int m = 0; m < 2; ++m) {
                    int mt = 2 * g + m;
                    size_t wb = ((size_t)(((l * 2 + icc) * 9 + tap) * 4 + mt) * 64 + lane) * 8;
                    Ah[m][dr] = *(const short8*)(w2h + wb);
                    Al[m][dr] = *(const short8*)(w2l + wb);
                }
            }
#pragma unroll
            for (int rr = 0; rr < 6; ++rr) {
                int off = ((4 * ng + rr) * 18 + (fr + dc)) * ICST + fq * 8;
                short8 bh = *(const short8*)(yt + off);
#pragma unroll
                for (int dr = 0; dr < 3; ++dr) {
                    int rl = rr - dr;
                    if (rl >= 0 && rl < 4) {
#pragma unroll
                        for (int m = 0; m < 2; ++m) {
                            acc[m][rl] = __builtin_amdgcn_mfma_f32_16x16x32_bf16(Ah[m][dr], bh, acc[m][rl], 0, 0, 0);
                            acc[m][rl] = __builtin_amdgcn_mfma_f32_16x16x32_bf16(Al[m][dr], bh, acc[m][rl], 0, 0, 0);
                        }
                    }
                }
            }
        }
        if (icc) {  // leaf epilogue: bias + relu + mixture accumulate
            float mx = mixw[(size_t)b * 8 + l];
#pragma unroll
            for (int m = 0; m < 2; ++m)
#pragma unroll
                for (int j = 0; j < 4; ++j) {
                    float bias = cb2[l * 64 + (2 * g + m) * 16 + fq * 4 + j];
#pragma unroll
                    for (int rl = 0; rl < 4; ++rl) {
                        float v = fmaxf(acc[m][rl][j] + bias, 0.f);
                        oacc[m][rl][j] = fmaf(mx, v, oacc[m][rl][j]);
                        acc[m][rl][j] = 0.f;
                    }
                }
        }
        __syncthreads();
    }

    // ---- store out1 [bl][64 oc][256 pos] fp32 ----
#pragma unroll
    for (int m = 0; m < 2; ++m)
#pragma unroll
        for (int rl = 0; rl < 4; ++rl)
#pragma unroll
            for (int j = 0; j < 4; ++j) {
                int oc = (2 * g + m) * 16 + fq * 4 + j;
                int pos = (4 * ng + rl) * 16 + fr;
                out1[((size_t)bl * 64 + oc) * 256 + pos] = oacc[m][rl][j];
            }
}

// ---------- fc: [bc][16384] @ [10][16384]^T + b ----------
__global__ __launch_bounds__(256) void k_fc(const float* __restrict__ out1, const float* __restrict__ fcw,
                                            const float* __restrict__ fcb, float* __restrict__ out, int boff) {
    __shared__ float red[4][OUTW_];
    int tid = threadIdx.x;
    int bl = blockIdx.x;
    const float4* flat = (const float4*)(out1 + (size_t)bl * FCIN_);
    float pj[OUTW_];
#pragma unroll
    for (int j = 0; j < OUTW_; ++j) pj[j] = 0.f;
    for (int i = tid; i < FCIN_ / 4; i += 256) {
        float4 v = flat[i];
#pragma unroll
        for (int j = 0; j < OUTW_; ++j) {
            float4 w = ((const float4*)(fcw + (size_t)j * FCIN_))[i];
            pj[j] += v.x * w.x + v.y * w.y + v.z * w.z + v.w * w.w;
        }
    }
#pragma unroll
    for (int j = 0; j < OUTW_; ++j) {
        float v = pj[j];
        for (int off = 32; off > 0; off >>= 1) v += __shfl_xor(v, off);
        if ((tid & 63) == 0) red[tid >> 6][j] = v;
    }
    __syncthreads();
    if (tid < OUTW_) {
        float s = red[0][tid] + red[1][tid] + red[2][tid] + red[3][tid] + fcb[tid];
        out[(size_t)(boff + bl) * OUTW_ + tid] = s;
    }
}

extern "C" void kernel_launch(void* const* d_in, const int* in_sizes, int n_in,
                              void* d_out, int out_size, void* d_ws, size_t ws_size,
                              hipStream_t stream) {
    const float* x   = (const float*)d_in[0];
    const float* nw  = (const float*)d_in[1];
    const float* nb  = (const float*)d_in[2];
    const float* w1  = (const float*)d_in[3];
    const float* cb1 = (const float*)d_in[4];
    const float* w2  = (const float*)d_in[5];
    const float* cb2 = (const float*)d_in[6];
    const float* fcw = (const float*)d_in[7];
    const float* fcb = (const float*)d_in[8];
    float* out = (float*)d_out;

    float*  ws   = (float*)d_ws;
    float*  mix  = ws;                        // 2048 f
    ushort* w1fh = (ushort*)(mix + 2048);     // 16384 us
    ushort* w1fl = w1fh + 16384;              // 16384 us
    ushort* w2h  = w1fl + 16384;              // 294912 us
    ushort* w2l  = w2h + 294912;              // 294912 us
    float*  out1 = (float*)(w2l + 294912);    // Bc * 16384 f

    // fixed bytes: 2048*4 + 2*16384*2 + 2*294912*2 = 1253376; out1 per sample = 65536 B
    long avail = (long)ws_size - 1253376L;
    int Bc = (int)(avail / 65536L);
    if (Bc > B_) Bc = B_;
    if (Bc < 1) Bc = 1;

    k_repack_w1f<<<16384 / 256, 256, 0, stream>>>(w1, w1fh, w1fl);
    k_repack_w2<<<294912 / 256, 256, 0, stream>>>(w2, w2h, w2l);
    k_mixture<<<B_, 256, 0, stream>>>(x, nw, nb, mix);

    for (int boff = 0; boff < B_; boff += Bc) {
        int bc = (B_ - boff < Bc) ? (B_ - boff) : Bc;
        k_fused<<<bc, 512, 0, stream>>>(x, w1fh, w1fl, cb1, w2h, w2l, cb2, mix, out1, boff);
        k_fc<<<bc, 256, 0, stream>>>(out1, fcw, fcb, out, boff);
    }
}

// Round 11
// 129.214 us; speedup vs baseline: 1.7997x; 1.0875x over previous
//
#include <hip/hip_runtime.h>
#include <cstdint>
#include <cstddef>

#define B_ 256
#define IW_ 3072
#define L_ 8
#define NN_ 7
#define FCIN_ 16384
#define OUTW_ 10
#define ICST 40            // ushorts per (row,col) cell: 32 ic + 8 pad
#define YPLANE (324 * ICST)
#define WCH 36864          // ushorts per (l,icc) conv2 weight chunk: [plane2][tap9][mt4][lane64][j8]

typedef short short8 __attribute__((ext_vector_type(8)));
typedef float f32x4 __attribute__((ext_vector_type(4)));

__device__ __forceinline__ ushort f2bf(float x) {
    uint u = __float_as_uint(x);
    return (ushort)((u + 0x7fffu + ((u >> 16) & 1u)) >> 16);
}
__device__ __forceinline__ float bf2f(ushort b) { return __uint_as_float(((uint)b) << 16); }

// ---------- repack conv1 weights into MFMA frag-linear hi/lo bf16 ----------
// layout: [l8][mt4][lane64][j8]; oc = mt*16 + (lane&15); k = (lane>>4)*8 + j (k=ic*9+tap, 27..31 pad)
__global__ void k_repack_w1f(const float* __restrict__ w1, ushort* __restrict__ w1fh,
                             ushort* __restrict__ w1fl) {
    int i = blockIdx.x * 256 + threadIdx.x;
    if (i >= 16384) return;
    int j    = i & 7;
    int lane = (i >> 3) & 63;
    int mt   = (i >> 9) & 3;
    int l    = i >> 11;
    int fr = lane & 15, fq = lane >> 4;
    int oc = mt * 16 + fr;
    int k = fq * 8 + j;
    float w = (k < 27) ? w1[(size_t)(l * 64 + oc) * 27 + k] : 0.f;
    ushort hb = f2bf(w);
    w1fh[i] = hb;
    w1fl[i] = f2bf(w - bf2f(hb));
}

// ---------- repack conv2 weights: single buffer [l8][icc2][plane2][tap9][mt4][lane64][j8] ----------
__global__ void k_repack_w2(const float* __restrict__ w2, ushort* __restrict__ w2hl) {
    int i = blockIdx.x * 256 + threadIdx.x;
    if (i >= 589824) return;
    int j     = i & 7;
    int lane  = (i >> 3) & 63;
    int mt    = (i >> 9) & 3;
    int tap   = (i >> 11) % 9;
    int plane = (i / 18432) & 1;
    int icc   = (i / 36864) & 1;
    int l     = i / 73728;
    int fr = lane & 15, fq = lane >> 4;
    int oc = mt * 16 + fr;
    int ic = icc * 32 + fq * 8 + j;
    float w = w2[(((size_t)l * 64 + oc) * 64 + ic) * 9 + tap];
    ushort hb = f2bf(w);
    w2hl[i] = plane ? f2bf(w - bf2f(hb)) : hb;
}

// ---------- mixture ----------
__global__ __launch_bounds__(256) void k_mixture(const float* __restrict__ x, const float* __restrict__ nw,
                                                 const float* __restrict__ nb, float* __restrict__ mix) {
    __shared__ float red[4 * NN_];
    __shared__ float bes[NN_];
    int b = blockIdx.x, tid = threadIdx.x;
    const float* xb = x + (size_t)b * IW_;
    float p[NN_];
#pragma unroll
    for (int n = 0; n < NN_; ++n) p[n] = 0.f;
    for (int i = tid; i < IW_; i += 256) {
        float xv = xb[i];
#pragma unroll
        for (int n = 0; n < NN_; ++n) p[n] = fmaf(xv, nw[n * IW_ + i], p[n]);
    }
#pragma unroll
    for (int n = 0; n < NN_; ++n) {
        float v = p[n];
        for (int off = 32; off > 0; off >>= 1) v += __shfl_xor(v, off);
        if ((tid & 63) == 0) red[(tid >> 6) * NN_ + n] = v;
    }
    __syncthreads();
    if (tid < NN_) {
        float s = red[tid] + red[NN_ + tid] + red[2 * NN_ + tid] + red[3 * NN_ + tid] + nb[tid];
        bes[tid] = 1.f / (1.f + expf(-s));
    }
    __syncthreads();
    if (tid < L_) {
        int leaf = tid;
        float b0 = bes[0];
        float t0 = ((leaf >> 2) & 1) ? b0 : 1.f - b0;
        float b1v = bes[1 + ((leaf >> 2) & 1)];
        float t1 = ((leaf >> 1) & 1) ? b1v : 1.f - b1v;
        float b2v = bes[3 + ((leaf >> 1) & 3)];
        float t2 = (leaf & 1) ? b2v : 1.f - b2v;
        mix[b * L_ + leaf] = t0 * t1 * t2;
    }
}

// ---------- fused conv1/conv2 (R10 chassis + LDS-staged conv2 weights, T14 split) ----------
// block = sample (grid 256 = 1/CU), 512 thr / 8 waves, 16 steps (8 leaves x 2 icc).
// Per step: [issue 9x uint4 global loads of this step's 72KB W2 chunk]  -> conv1 MFMA/pack
// (hides the load latency) -> ds_write staged regs -> barrier -> conv2 reads A AND y from LDS.
__global__ __launch_bounds__(512, 2) void k_fused(const float* __restrict__ x,
                                                  const ushort* __restrict__ w1fh, const ushort* __restrict__ w1fl,
                                                  const float* __restrict__ cb1,
                                                  const ushort* __restrict__ w2hl,
                                                  const float* __restrict__ cb2, const float* __restrict__ mixw,
                                                  float* __restrict__ out1, int boff) {
    __shared__ __align__(16) ushort smem[YPLANE + WCH];   // yt 25.9 KB | wlds 72 KB = 97.3 KB
    ushort* yt = smem;
    ushort* wlds = smem + YPLANE;
    float* xpad = (float*)smem;                            // prologue-only alias (13.9 KB < yt)

    int tid = threadIdx.x;
    int bl = blockIdx.x;
    int b = boff + bl;
    int lane = tid & 63, wid = tid >> 6;
    int fr = lane & 15, fq = lane >> 4;
    int g = wid & 1, ng = wid >> 1;               // conv2: mts {2g,2g+1}, rows {4ng..4ng+3}

    // ---- prologue: xpad zero + fill ----
    for (int i = tid; i < 3 * 34 * 34; i += 512) xpad[i] = 0.f;
    __syncthreads();
    for (int i = tid; i < 3072; i += 512) {
        int ch = i >> 10, rr = (i >> 5) & 31, cc = i & 31;
        xpad[(ch * 34 + rr + 1) * 34 + cc + 1] = x[(size_t)b * IW_ + i];
    }
    __syncthreads();

    // ---- leaf-invariant conv1 im2col B-frags, single bf16 (RTN) ----
    short8 Bh[8];
#pragma unroll
    for (int i = 0; i < 8; ++i) {
        int nt = wid * 8 + i;
        int pos = nt * 16 + fr;          // pre-pool position, row-major 32x32
        int r = pos >> 5, c = pos & 31;
#pragma unroll
        for (int j = 0; j < 8; ++j) {
            int k = fq * 8 + j;          // k = ic*9 + tap
            float xv = 0.f;
            if (k < 27) {
                int ic = k / 9;
                int tap = k - ic * 9;
                int dr = tap / 3, dc = tap - dr * 3;
                xv = xpad[(ic * 34 + r + dr) * 34 + (c + dc)];
            }
            Bh[i][j] = (short)f2bf(xv);
        }
    }
    __syncthreads();
    {   // zero y plane (borders stay zero forever)
        uint4 z; z.x = z.y = z.z = z.w = 0u;
        for (int i = tid; i < YPLANE / 8; i += 512) ((uint4*)yt)[i] = z;
    }
    __syncthreads();

    f32x4 acc[2][4], oacc[2][4];
#pragma unroll
    for (int m = 0; m < 2; ++m)
#pragma unroll
        for (int rl = 0; rl < 4; ++rl) { acc[m][rl] = (f32x4)0.f; oacc[m][rl] = (f32x4)0.f; }

    for (int s = 0; s < 16; ++s) {
        int l = s >> 1, icc = s & 1;

        // ---- issue this step's W2 chunk loads EARLY (latency hides under conv1) ----
        uint4 stg[9];
        {
            const uint4* wsrc = (const uint4*)(w2hl + (size_t)(l * 2 + icc) * WCH);
#pragma unroll
            for (int r = 0; r < 9; ++r) stg[r] = wsrc[r * 512 + tid];
        }

        // ---- conv1 phase: 32 chans (2 mtiles) of this icc chunk into y tile ----
#pragma unroll
        for (int mt2 = 0; mt2 < 2; ++mt2) {
            int mtg = icc * 2 + mt2;
            short8 ah = *(const short8*)(w1fh + ((size_t)(l * 4 + mtg) * 64 + lane) * 8);
            short8 al = *(const short8*)(w1fl + ((size_t)(l * 4 + mtg) * 64 + lane) * 8);
            f32x4 a1[8];
#pragma unroll
            for (int i = 0; i < 8; ++i) {
                f32x4 t = (f32x4)0.f;
                t = __builtin_amdgcn_mfma_f32_16x16x32_bf16(ah, Bh[i], t, 0, 0, 0);
                t = __builtin_amdgcn_mfma_f32_16x16x32_bf16(al, Bh[i], t, 0, 0, 0);
                a1[i] = t;
            }
            float4 bias4 = *(const float4*)(cb1 + l * 64 + mtg * 16 + fq * 4);
            float bb[4] = {bias4.x, bias4.y, bias4.z, bias4.w};
#pragma unroll
            for (int g4 = 0; g4 < 4; ++g4) {
                int i = (g4 & 1) + (g4 >> 1) * 4;   // {0,1,4,5}; pool partner i+2
                ushort hb[4];
#pragma unroll
                for (int j2 = 0; j2 < 4; ++j2) {
                    float m0 = fmaxf(a1[i][j2], a1[i + 2][j2]);
                    float m1 = fmaxf(m0, __shfl_xor(m0, 1));
                    float v = fmaxf(m1 + bb[j2], 0.f);
                    hb[j2] = f2bf(v);
                }
                if ((fr & 1) == 0) {
                    int pr = 2 * wid + (i >> 2);
                    int pc = ((i & 1) * 16 + fr) >> 1;
                    int off = ((pr + 1) * 18 + (pc + 1)) * ICST + mt2 * 16 + fq * 4;
                    uint2 H;
                    H.x = (uint)hb[0] | ((uint)hb[1] << 16);
                    H.y = (uint)hb[2] | ((uint)hb[3] << 16);
                    *(uint2*)&yt[off] = H;
                }
            }
        }

        // ---- write staged W2 chunk to LDS (vmcnt auto-waits), then publish ----
#pragma unroll
        for (int r = 0; r < 9; ++r) *(uint4*)&wlds[(r * 512 + tid) * 8] = stg[r];
        __syncthreads();

        // ---- conv2 phase: dc-major, A from LDS, input-row reuse across row-taps ----
#pragma unroll
        for (int dc = 0; dc < 3; ++dc) {
            short8 Ah[2][3], Al[2][3];
#pragma unroll
            for (int dr = 0; dr < 3; ++dr) {
                int tap = dr * 3 + dc;
#pragma unroll
                for (int m = 0; m < 2; ++m) {
                    int mt = 2 * g + m;
                    Ah[m][dr] = *(const short8*)&wlds[((tap * 4 + mt) * 64 + lane) * 8];
                    Al[m][dr] = *(const short8*)&wlds[(((9 + tap) * 4 + mt) * 64 + lane) * 8];
                }
            }
#pragma unroll
            for (int rr = 0; rr < 6; ++rr) {
                int off = ((4 * ng + rr) * 18 + (fr + dc)) * ICST + fq * 8;
                short8 bh = *(const short8*)(yt + off);
#pragma unroll
                for (int dr = 0; dr < 3; ++dr) {
                    int rl = rr - dr;
                    if (rl >= 0 && rl < 4) {
#pragma unroll
                        for (int m = 0; m < 2; ++m) {
                            acc[m][rl] = __builtin_amdgcn_mfma_f32_16x16x32_bf16(Ah[m][dr], bh, acc[m][rl], 0, 0, 0);
                            acc[m][rl] = __builtin_amdgcn_mfma_f32_16x16x32_bf16(Al[m][dr], bh, acc[m][rl], 0, 0, 0);
                        }
                    }
                }
            }
        }
        if (icc) {  // leaf epilogue: bias + relu + mixture accumulate
            float mx = mixw[(size_t)b * 8 + l];
#pragma unroll
            for (int m = 0; m < 2; ++m)
#pragma unroll
                for (int j = 0; j < 4; ++j) {
                    float bias = cb2[l * 64 + (2 * g + m) * 16 + fq * 4 + j];
#pragma unroll
                    for (int rl = 0; rl < 4; ++rl) {
                        float v = fmaxf(acc[m][rl][j] + bias, 0.f);
                        oacc[m][rl][j] = fmaf(mx, v, oacc[m][rl][j]);
                        acc[m][rl][j] = 0.f;
                    }
                }
        }
        __syncthreads();
    }

    // ---- store out1 [bl][64 oc][256 pos] fp32 ----
#pragma unroll
    for (int m = 0; m < 2; ++m)
#pragma unroll
        for (int rl = 0; rl < 4; ++rl)
#pragma unroll
            for (int j = 0; j < 4; ++j) {
                int oc = (2 * g + m) * 16 + fq * 4 + j;
                int pos = (4 * ng + rl) * 16 + fr;
                out1[((size_t)bl * 64 + oc) * 256 + pos] = oacc[m][rl][j];
            }
}

// ---------- fc: [bc][16384] @ [10][16384]^T + b ----------
__global__ __launch_bounds__(256) void k_fc(const float* __restrict__ out1, const float* __restrict__ fcw,
                                            const float* __restrict__ fcb, float* __restrict__ out, int boff) {
    __shared__ float red[4][OUTW_];
    int tid = threadIdx.x;
    int bl = blockIdx.x;
    const float4* flat = (const float4*)(out1 + (size_t)bl * FCIN_);
    float pj[OUTW_];
#pragma unroll
    for (int j = 0; j < OUTW_; ++j) pj[j] = 0.f;
    for (int i = tid; i < FCIN_ / 4; i += 256) {
        float4 v = flat[i];
#pragma unroll
        for (int j = 0; j < OUTW_; ++j) {
            float4 w = ((const float4*)(fcw + (size_t)j * FCIN_))[i];
            pj[j] += v.x * w.x + v.y * w.y + v.z * w.z + v.w * w.w;
        }
    }
#pragma unroll
    for (int j = 0; j < OUTW_; ++j) {
        float v = pj[j];
        for (int off = 32; off > 0; off >>= 1) v += __shfl_xor(v, off);
        if ((tid & 63) == 0) red[tid >> 6][j] = v;
    }
    __syncthreads();
    if (tid < OUTW_) {
        float s = red[0][tid] + red[1][tid] + red[2][tid] + red[3][tid] + fcb[tid];
        out[(size_t)(boff + bl) * OUTW_ + tid] = s;
    }
}

extern "C" void kernel_launch(void* const* d_in, const int* in_sizes, int n_in,
                              void* d_out, int out_size, void* d_ws, size_t ws_size,
                              hipStream_t stream) {
    const float* x   = (const float*)d_in[0];
    const float* nw  = (const float*)d_in[1];
    const float* nb  = (const float*)d_in[2];
    const float* w1  = (const float*)d_in[3];
    const float* cb1 = (const float*)d_in[4];
    const float* w2  = (const float*)d_in[5];
    const float* cb2 = (const float*)d_in[6];
    const float* fcw = (const float*)d_in[7];
    const float* fcb = (const float*)d_in[8];
    float* out = (float*)d_out;

    float*  ws   = (float*)d_ws;
    float*  mix  = ws;                        // 2048 f
    ushort* w1fh = (ushort*)(mix + 2048);     // 16384 us
    ushort* w1fl = w1fh + 16384;              // 16384 us
    ushort* w2hl = w1fl + 16384;              // 589824 us (hi|lo interleaved per (l,icc) chunk)
    float*  out1 = (float*)(w2hl + 589824);   // Bc * 16384 f

    // fixed bytes: 2048*4 + 2*16384*2 + 589824*2 = 1253376; out1 per sample = 65536 B
    long avail = (long)ws_size - 1253376L;
    int Bc = (int)(avail / 65536L);
    if (Bc > B_) Bc = B_;
    if (Bc < 1) Bc = 1;

    k_repack_w1f<<<16384 / 256, 256, 0, stream>>>(w1, w1fh, w1fl);
    k_repack_w2<<<589824 / 256, 256, 0, stream>>>(w2, w2hl);
    k_mixture<<<B_, 256, 0, stream>>>(x, nw, nb, mix);

    for (int boff = 0; boff < B_; boff += Bc) {
        int bc = (B_ - boff < Bc) ? (B_ - boff) : Bc;
        k_fused<<<bc, 512, 0, stream>>>(x, w1fh, w1fl, cb1, w2hl, cb2, mix, out1, boff);
        k_fc<<<bc, 256, 0, stream>>>(out1, fcw, fcb, out, boff);
    }
}